// Round 1
// baseline (381.138 us; speedup 1.0000x reference)
//
#include <hip/hip_runtime.h>
#include <stdint.h>

#define SCALE 0.04419417382415922f  // 1/sqrt(512)

typedef __bf16 bf16x8 __attribute__((ext_vector_type(8)));
typedef float f32x4 __attribute__((ext_vector_type(4)));
typedef uint16_t u16x8 __attribute__((ext_vector_type(8)));

static __device__ __forceinline__ uint16_t f2bf(float f) {
  union { float f; uint32_t u; } v; v.f = f;
  uint32_t u = v.u;
  return (uint16_t)((u + 0x7FFFu + ((u >> 16) & 1u)) >> 16);
}
static __device__ __forceinline__ float bf2f(uint16_t h) {
  union { uint32_t u; float f; } v; v.u = ((uint32_t)h) << 16;
  return v.f;
}

static __device__ __forceinline__ void gload16(const void* g, void* l) {
  __builtin_amdgcn_global_load_lds(
      (__attribute__((address_space(1))) void*)g,
      (__attribute__((address_space(3))) void*)l, 16, 0, 0);
}

// ---------------- conversions / packing ----------------

__global__ __launch_bounds__(256)
void convert_x(const float* __restrict__ x, uint16_t* __restrict__ xb) {
  size_t i = ((size_t)blockIdx.x * 256 + threadIdx.x) * 8;
  float4 a = *(const float4*)(x + i);
  float4 b = *(const float4*)(x + i + 4);
  u16x8 o;
  o[0] = f2bf(a.x); o[1] = f2bf(a.y); o[2] = f2bf(a.z); o[3] = f2bf(a.w);
  o[4] = f2bf(b.x); o[5] = f2bf(b.y); o[6] = f2bf(b.z); o[7] = f2bf(b.w);
  *(u16x8*)(xb + i) = o;
}

// wqkvT[n][k] (n in [0,1536), k in [0,512)) = W{q,k,v}[k][n%512] (* SCALE for q)
__global__ __launch_bounds__(256)
void pack_w(const float* __restrict__ Wq, const float* __restrict__ Wk,
            const float* __restrict__ Wv, uint16_t* __restrict__ wt) {
  __shared__ float tile[64][65];
  const int k0 = blockIdx.x * 64, n0 = blockIdx.y * 64, m = blockIdx.z;
  const float* W = (m == 0) ? Wq : ((m == 1) ? Wk : Wv);
  const float scl = (m == 0) ? SCALE : 1.0f;
  const int t = threadIdx.x, r = t >> 2, c0 = (t & 3) * 16;
  #pragma unroll
  for (int j = 0; j < 4; j++) {
    float4 v = *(const float4*)&W[(size_t)(k0 + r) * 512 + n0 + c0 + j * 4];
    tile[r][c0 + j * 4 + 0] = v.x; tile[r][c0 + j * 4 + 1] = v.y;
    tile[r][c0 + j * 4 + 2] = v.z; tile[r][c0 + j * 4 + 3] = v.w;
  }
  __syncthreads();
  u16x8 o0, o1;
  #pragma unroll
  for (int e = 0; e < 8; e++) {
    o0[e] = f2bf(tile[c0 + e][r] * scl);
    o1[e] = f2bf(tile[c0 + 8 + e][r] * scl);
  }
  uint16_t* dst = wt + (size_t)(m * 512 + n0 + r) * 512 + k0 + c0;
  *(u16x8*)dst = o0;
  *(u16x8*)(dst + 8) = o1;
}

// woT[n][k] = sum_h Wo[h*512+k][n]
__global__ __launch_bounds__(256)
void pack_wo(const float* __restrict__ Wo, uint16_t* __restrict__ woT) {
  __shared__ float tile[64][65];
  const int k0 = blockIdx.x * 64, n0 = blockIdx.y * 64;
  const int t = threadIdx.x, r = t >> 2, c0 = (t & 3) * 16;
  float av[16];
  #pragma unroll
  for (int e = 0; e < 16; e++) av[e] = 0.f;
  for (int h = 0; h < 8; h++) {
    const float* src = &Wo[(size_t)(h * 512 + k0 + r) * 512 + n0 + c0];
    #pragma unroll
    for (int j = 0; j < 4; j++) {
      float4 v = *(const float4*)(src + j * 4);
      av[j * 4 + 0] += v.x; av[j * 4 + 1] += v.y;
      av[j * 4 + 2] += v.z; av[j * 4 + 3] += v.w;
    }
  }
  #pragma unroll
  for (int e = 0; e < 16; e++) tile[r][c0 + e] = av[e];
  __syncthreads();
  u16x8 o0, o1;
  #pragma unroll
  for (int e = 0; e < 8; e++) {
    o0[e] = f2bf(tile[c0 + e][r]);
    o1[e] = f2bf(tile[c0 + 8 + e][r]);
  }
  uint16_t* dst = woT + (size_t)(n0 + r) * 512 + k0 + c0;
  *(u16x8*)dst = o0;
  *(u16x8*)(dst + 8) = o1;
}

__global__ void pack_bias(const float* __restrict__ bq, const float* __restrict__ bk,
                          const float* __restrict__ bv, float* __restrict__ bqkv) {
  int i = blockIdx.x * 256 + threadIdx.x;
  if (i < 512) bqkv[i] = bq[i] * SCALE;
  else if (i < 1024) bqkv[i] = bk[i - 512];
  else if (i < 1536) bqkv[i] = bv[i - 1024];
}

// Vt[b][d][s] = qkv[b*4096+s][1024+d]
__global__ __launch_bounds__(256)
void transpose_v(const uint16_t* __restrict__ qkv, uint16_t* __restrict__ Vt) {
  __shared__ uint16_t tile[64][72];
  const int s0 = blockIdx.x * 64, d0 = blockIdx.y * 64, b = blockIdx.z;
  const int t = threadIdx.x, r = t >> 2, c0 = (t & 3) * 16;
  const uint16_t* src = qkv + ((size_t)(b * 4096 + s0 + r)) * 1536 + 1024 + d0 + c0;
  *(u16x8*)&tile[r][c0] = *(const u16x8*)src;
  *(u16x8*)&tile[r][c0 + 8] = *(const u16x8*)(src + 8);
  __syncthreads();
  u16x8 o0, o1;
  #pragma unroll
  for (int e = 0; e < 8; e++) { o0[e] = tile[c0 + e][r]; o1[e] = tile[c0 + 8 + e][r]; }
  uint16_t* dst = Vt + ((size_t)b * 512 + d0 + r) * 4096 + s0 + c0;
  *(u16x8*)dst = o0;
  *(u16x8*)(dst + 8) = o1;
}

// ---------------- GEMM: C = A @ Bt^T (+bias), bf16 in, bf16/f32 out ----------------
// m97 structure: 128x128 tile, BK=32, 4 waves, 4x4 frags of 16x16x32.
template<int F32OUT>
__global__ __launch_bounds__(256, 2)
void gemm_bt(const uint16_t* __restrict__ A, const uint16_t* __restrict__ Bt,
             const float* __restrict__ bias, void* __restrict__ Cout,
             int M, int N, int K, int lda, int ldb, int ldc,
             long long aZ, long long bZ, long long cZ) {
  __shared__ uint16_t As[128 * 32];
  __shared__ uint16_t Bs[128 * 32];
  const int nbn = N >> 7;
  const int nwg = (M >> 7) * nbn;
  int id = blockIdx.x;
  id = (id & 7) * (nwg >> 3) + (id >> 3);  // XCD swizzle (all grids %8==0)
  const int bm = id / nbn, bn = id % nbn;
  const long long z = blockIdx.z;
  A += z * aZ; Bt += z * bZ;

  const int t = threadIdx.x;
  const int lane = t & 63, w = t >> 6;
  const int wr = w >> 1, wc = w & 1;
  const size_t m0 = (size_t)bm * 128, n0 = (size_t)bn * 128;

  f32x4 acc[4][4];
  #pragma unroll
  for (int i = 0; i < 4; i++)
    #pragma unroll
    for (int j = 0; j < 4; j++) acc[i][j] = (f32x4)(0.f);

  const uint16_t* ag = A + (m0 + (size_t)(t >> 2)) * lda + (t & 3) * 8;
  const uint16_t* bg = Bt + (n0 + (size_t)(t >> 2)) * ldb + (t & 3) * 8;
  uint16_t* la = &As[w * 512];
  uint16_t* lb = &Bs[w * 512];

  for (int k0 = 0; k0 < K; k0 += 32) {
    gload16(ag, la);
    gload16(ag + (size_t)64 * lda, la + 2048);
    gload16(bg, lb);
    gload16(bg + (size_t)64 * ldb, lb + 2048);
    ag += 32; bg += 32;
    __syncthreads();
    bf16x8 a[4], b[4];
    const uint16_t* pa = &As[(wr * 64 + (lane & 15)) * 32 + (lane >> 4) * 8];
    const uint16_t* pb = &Bs[(wc * 64 + (lane & 15)) * 32 + (lane >> 4) * 8];
    #pragma unroll
    for (int i = 0; i < 4; i++) a[i] = *(const bf16x8*)(pa + i * 512);
    #pragma unroll
    for (int i = 0; i < 4; i++) b[i] = *(const bf16x8*)(pb + i * 512);
    #pragma unroll
    for (int mi = 0; mi < 4; mi++)
      #pragma unroll
      for (int ni = 0; ni < 4; ni++)
        acc[mi][ni] = __builtin_amdgcn_mfma_f32_16x16x32_bf16(a[mi], b[ni], acc[mi][ni], 0, 0, 0);
    __syncthreads();
  }

  const int crow = wr * 64 + ((lane >> 4) << 2);
  const int ccol = wc * 64 + (lane & 15);
  float bvv[4];
  #pragma unroll
  for (int ni = 0; ni < 4; ni++) bvv[ni] = bias ? bias[n0 + ccol + ni * 16] : 0.f;
  #pragma unroll
  for (int mi = 0; mi < 4; mi++) {
    #pragma unroll
    for (int r = 0; r < 4; r++) {
      size_t gr = m0 + crow + mi * 16 + r;
      #pragma unroll
      for (int ni = 0; ni < 4; ni++) {
        float v = acc[mi][ni][r] + bvv[ni];
        size_t idx = gr * (size_t)ldc + n0 + ccol + ni * 16;
        if (F32OUT) ((float*)Cout)[z * cZ + idx] = v;
        else ((uint16_t*)Cout)[z * cZ + idx] = f2bf(v);
      }
    }
  }
}

// ---------------- row softmax, in-place on bf16 [4096][4096] per z ----------------
__global__ __launch_bounds__(256)
void softmax_rows(uint16_t* __restrict__ Sb) {
  const int t = threadIdx.x;
  uint16_t* p = Sb + ((size_t)blockIdx.y * 4096 + blockIdx.x) * 4096 + t * 16;
  u16x8 v0 = *(const u16x8*)p;
  u16x8 v1 = *(const u16x8*)(p + 8);
  float f[16];
  #pragma unroll
  for (int i = 0; i < 8; i++) { f[i] = bf2f(v0[i]); f[8 + i] = bf2f(v1[i]); }
  float mx = f[0];
  #pragma unroll
  for (int i = 1; i < 16; i++) mx = fmaxf(mx, f[i]);
  #pragma unroll
  for (int o = 32; o; o >>= 1) mx = fmaxf(mx, __shfl_xor(mx, o));
  __shared__ float redm[4], reds[4];
  const int w = t >> 6;
  if ((t & 63) == 0) redm[w] = mx;
  __syncthreads();
  mx = fmaxf(fmaxf(redm[0], redm[1]), fmaxf(redm[2], redm[3]));
  float s = 0.f;
  #pragma unroll
  for (int i = 0; i < 16; i++) { f[i] = __expf(f[i] - mx); s += f[i]; }
  #pragma unroll
  for (int o = 32; o; o >>= 1) s += __shfl_xor(s, o);
  if ((t & 63) == 0) reds[w] = s;
  __syncthreads();
  s = (reds[0] + reds[1]) + (reds[2] + reds[3]);
  const float inv = 1.f / s;
  u16x8 o0, o1;
  #pragma unroll
  for (int i = 0; i < 8; i++) { o0[i] = f2bf(f[i] * inv); o1[i] = f2bf(f[8 + i] * inv); }
  *(u16x8*)p = o0;
  *(u16x8*)(p + 8) = o1;
}

// ---------------- launch ----------------

extern "C" void kernel_launch(void* const* d_in, const int* in_sizes, int n_in,
                              void* d_out, int out_size, void* d_ws, size_t ws_size,
                              hipStream_t stream) {
  const float* x   = (const float*)d_in[0];
  const float* Wq  = (const float*)d_in[1];
  const float* bq  = (const float*)d_in[2];
  const float* Wk  = (const float*)d_in[3];
  const float* bk  = (const float*)d_in[4];
  const float* Wv  = (const float*)d_in[5];
  const float* bvp = (const float*)d_in[6];
  const float* Wo  = (const float*)d_in[7];
  const float* bo  = (const float*)d_in[8];
  float* out = (float*)d_out;

  char* ws = (char*)d_ws;
  uint16_t* xb    = (uint16_t*)(ws);                          // 16 MB
  uint16_t* qkv   = (uint16_t*)(ws + ((size_t)16 << 20));     // 48 MB
  uint16_t* Sbuf  = (uint16_t*)(ws + ((size_t)64 << 20));     // 64 MB (2 batches)
  uint16_t* Vt    = (uint16_t*)(ws + ((size_t)128 << 20));    // 16 MB
  uint16_t* attn  = (uint16_t*)(ws + ((size_t)144 << 20));    // 16 MB
  uint16_t* wqkvT = (uint16_t*)(ws + ((size_t)160 << 20));    // 1.5 MB
  uint16_t* woT   = (uint16_t*)(ws + ((size_t)162 << 20));    // 0.5 MB
  float*    bqkv  = (float*)   (ws + ((size_t)163 << 20));    // 6 KB

  convert_x<<<dim3(4096), dim3(256), 0, stream>>>(x, xb);
  pack_w<<<dim3(8, 8, 3), dim3(256), 0, stream>>>(Wq, Wk, Wv, wqkvT);
  pack_wo<<<dim3(8, 8), dim3(256), 0, stream>>>(Wo, woT);
  pack_bias<<<dim3(6), dim3(256), 0, stream>>>(bq, bk, bvp, bqkv);

  // QKV projection: [16384,512] @ [1536,512]^T -> [16384,1536] bf16
  gemm_bt<0><<<dim3(1536, 1, 1), dim3(256), 0, stream>>>(
      xb, wqkvT, bqkv, qkv, 16384, 1536, 512, 512, 512, 1536, 0, 0, 0);

  transpose_v<<<dim3(64, 8, 4), dim3(256), 0, stream>>>(qkv, Vt);

  for (int pair = 0; pair < 2; pair++) {
    const uint16_t* qbase = qkv + (size_t)pair * 2 * 4096 * 1536;
    // scores: Q @ K^T (scale baked into Q), per batch z=0,1
    gemm_bt<0><<<dim3(1024, 1, 2), dim3(256), 0, stream>>>(
        qbase, qbase + 512, nullptr, Sbuf,
        4096, 4096, 512, 1536, 1536, 4096,
        (long long)4096 * 1536, (long long)4096 * 1536, (long long)4096 * 4096);
    softmax_rows<<<dim3(4096, 2), dim3(256), 0, stream>>>(Sbuf);
    // attn = P @ V  (Vt rows are d, contiguous over k)
    gemm_bt<0><<<dim3(128, 1, 2), dim3(256), 0, stream>>>(
        Sbuf, Vt + (size_t)pair * 2 * 512 * 4096, nullptr,
        attn + (size_t)pair * 2 * 4096 * 512,
        4096, 512, 4096, 4096, 4096, 512,
        (long long)4096 * 4096, (long long)512 * 4096, (long long)4096 * 512);
  }

  // out = attn @ WoSum + bo  (f32 out)
  gemm_bt<1><<<dim3(512, 1, 1), dim3(256), 0, stream>>>(
      attn, woT, bo, out, 16384, 512, 512, 512, 512, 512, 0, 0, 0);
}

// Round 2
// 287.173 us; speedup vs baseline: 1.3272x; 1.3272x over previous
//
#include <hip/hip_runtime.h>
#include <stdint.h>

#define SCALE 0.04419417382415922f  // 1/sqrt(512)

typedef __bf16 bf16x8 __attribute__((ext_vector_type(8)));
typedef float f32x4 __attribute__((ext_vector_type(4)));
typedef uint16_t u16x8 __attribute__((ext_vector_type(8)));

static __device__ __forceinline__ uint16_t f2bf(float f) {
  union { float f; uint32_t u; } v; v.f = f;
  uint32_t u = v.u;
  return (uint16_t)((u + 0x7FFFu + ((u >> 16) & 1u)) >> 16);
}
static __device__ __forceinline__ float bf2f(uint16_t h) {
  union { uint32_t u; float f; } v; v.u = ((uint32_t)h) << 16;
  return v.f;
}

static __device__ __forceinline__ void gload16(const void* g, void* l) {
  __builtin_amdgcn_global_load_lds(
      (__attribute__((address_space(1))) void*)g,
      (__attribute__((address_space(3))) void*)l, 16, 0, 0);
}

// ---------------- conversions / packing (unchanged, R1-verified) ----------------

__global__ __launch_bounds__(256)
void convert_x(const float* __restrict__ x, uint16_t* __restrict__ xb) {
  size_t i = ((size_t)blockIdx.x * 256 + threadIdx.x) * 8;
  float4 a = *(const float4*)(x + i);
  float4 b = *(const float4*)(x + i + 4);
  u16x8 o;
  o[0] = f2bf(a.x); o[1] = f2bf(a.y); o[2] = f2bf(a.z); o[3] = f2bf(a.w);
  o[4] = f2bf(b.x); o[5] = f2bf(b.y); o[6] = f2bf(b.z); o[7] = f2bf(b.w);
  *(u16x8*)(xb + i) = o;
}

__global__ __launch_bounds__(256)
void pack_w(const float* __restrict__ Wq, const float* __restrict__ Wk,
            const float* __restrict__ Wv, uint16_t* __restrict__ wt) {
  __shared__ float tile[64][65];
  const int k0 = blockIdx.x * 64, n0 = blockIdx.y * 64, m = blockIdx.z;
  const float* W = (m == 0) ? Wq : ((m == 1) ? Wk : Wv);
  const float scl = (m == 0) ? SCALE : 1.0f;
  const int t = threadIdx.x, r = t >> 2, c0 = (t & 3) * 16;
  #pragma unroll
  for (int j = 0; j < 4; j++) {
    float4 v = *(const float4*)&W[(size_t)(k0 + r) * 512 + n0 + c0 + j * 4];
    tile[r][c0 + j * 4 + 0] = v.x; tile[r][c0 + j * 4 + 1] = v.y;
    tile[r][c0 + j * 4 + 2] = v.z; tile[r][c0 + j * 4 + 3] = v.w;
  }
  __syncthreads();
  u16x8 o0, o1;
  #pragma unroll
  for (int e = 0; e < 8; e++) {
    o0[e] = f2bf(tile[c0 + e][r] * scl);
    o1[e] = f2bf(tile[c0 + 8 + e][r] * scl);
  }
  uint16_t* dst = wt + (size_t)(m * 512 + n0 + r) * 512 + k0 + c0;
  *(u16x8*)dst = o0;
  *(u16x8*)(dst + 8) = o1;
}

__global__ __launch_bounds__(256)
void pack_wo(const float* __restrict__ Wo, uint16_t* __restrict__ woT) {
  __shared__ float tile[64][65];
  const int k0 = blockIdx.x * 64, n0 = blockIdx.y * 64;
  const int t = threadIdx.x, r = t >> 2, c0 = (t & 3) * 16;
  float av[16];
  #pragma unroll
  for (int e = 0; e < 16; e++) av[e] = 0.f;
  for (int h = 0; h < 8; h++) {
    const float* src = &Wo[(size_t)(h * 512 + k0 + r) * 512 + n0 + c0];
    #pragma unroll
    for (int j = 0; j < 4; j++) {
      float4 v = *(const float4*)(src + j * 4);
      av[j * 4 + 0] += v.x; av[j * 4 + 1] += v.y;
      av[j * 4 + 2] += v.z; av[j * 4 + 3] += v.w;
    }
  }
  #pragma unroll
  for (int e = 0; e < 16; e++) tile[r][c0 + e] = av[e];
  __syncthreads();
  u16x8 o0, o1;
  #pragma unroll
  for (int e = 0; e < 8; e++) {
    o0[e] = f2bf(tile[c0 + e][r]);
    o1[e] = f2bf(tile[c0 + 8 + e][r]);
  }
  uint16_t* dst = woT + (size_t)(n0 + r) * 512 + k0 + c0;
  *(u16x8*)dst = o0;
  *(u16x8*)(dst + 8) = o1;
}

__global__ void pack_bias(const float* __restrict__ bq, const float* __restrict__ bk,
                          const float* __restrict__ bv, float* __restrict__ bqkv) {
  int i = blockIdx.x * 256 + threadIdx.x;
  if (i < 512) bqkv[i] = bq[i] * SCALE;
  else if (i < 1024) bqkv[i] = bk[i - 512];
  else if (i < 1536) bqkv[i] = bv[i - 1024];
}

__global__ __launch_bounds__(256)
void transpose_v(const uint16_t* __restrict__ qkv, uint16_t* __restrict__ Vt) {
  __shared__ uint16_t tile[64][72];
  const int s0 = blockIdx.x * 64, d0 = blockIdx.y * 64, b = blockIdx.z;
  const int t = threadIdx.x, r = t >> 2, c0 = (t & 3) * 16;
  const uint16_t* src = qkv + ((size_t)(b * 4096 + s0 + r)) * 1536 + 1024 + d0 + c0;
  *(u16x8*)&tile[r][c0] = *(const u16x8*)src;
  *(u16x8*)&tile[r][c0 + 8] = *(const u16x8*)(src + 8);
  __syncthreads();
  u16x8 o0, o1;
  #pragma unroll
  for (int e = 0; e < 8; e++) { o0[e] = tile[c0 + e][r]; o1[e] = tile[c0 + 8 + e][r]; }
  uint16_t* dst = Vt + ((size_t)b * 512 + d0 + r) * 4096 + s0 + c0;
  *(u16x8*)dst = o0;
  *(u16x8*)(dst + 8) = o1;
}

// ---------------- GEMM v2: dbuf single-barrier + coalesced epilogue ----------------
// MODE 0: bf16 out (+bias)             [QKV]
// MODE 1: f32 out (+bias), direct      [final]
// MODE 2: exp(acc)->bf16 + row-sum partials [scores]
// MODE 3: bf16 out scaled by inv_sum[row]   [PV]
template<int MODE>
__global__ __launch_bounds__(256, 2)
void gemm2(const uint16_t* __restrict__ A, const uint16_t* __restrict__ Bt,
           const float* __restrict__ bias, void* __restrict__ Cout,
           float* __restrict__ sums,
           int M, int N, int K, int lda, int ldb, int ldc,
           long long aZ, long long bZ, long long cZ, long long sZ) {
  __shared__ __align__(16) uint16_t SH[16384];  // 32KB: As[2][4096] | Bs[2][4096]
  uint16_t* As = SH;
  uint16_t* Bs = SH + 8192;

  const int nbn = N >> 7;
  const int nwg = (M >> 7) * nbn;
  int id = blockIdx.x;
  id = (id & 7) * (nwg >> 3) + (id >> 3);  // XCD swizzle (all nwg % 8 == 0)
  const int bm = id / nbn, bn = id % nbn;
  const long long z = blockIdx.z;
  A += z * aZ; Bt += z * bZ;

  const int t = threadIdx.x;
  const int lane = t & 63, w = t >> 6;
  const int wr = w >> 1, wc = w & 1;
  const size_t m0 = (size_t)bm * 128, n0 = (size_t)bn * 128;

  f32x4 acc[4][4];
  #pragma unroll
  for (int i = 0; i < 4; i++)
    #pragma unroll
    for (int j = 0; j < 4; j++) acc[i][j] = (f32x4)(0.f);

  const uint16_t* ag = A + (m0 + (size_t)(t >> 2)) * lda + (t & 3) * 8;
  const uint16_t* bg = Bt + (n0 + (size_t)(t >> 2)) * ldb + (t & 3) * 8;

  auto stage = [&](int buf) {
    uint16_t* la = As + buf * 4096 + w * 512;  // wave-uniform dest; HW adds lane*16B
    uint16_t* lb = Bs + buf * 4096 + w * 512;
    gload16(ag, la);
    gload16(ag + (size_t)64 * lda, la + 2048);
    gload16(bg, lb);
    gload16(bg + (size_t)64 * ldb, lb + 2048);
    ag += 32; bg += 32;
  };
  auto compute = [&](int buf) {
    const uint16_t* pa = As + buf * 4096 + (wr * 64 + (lane & 15)) * 32 + (lane >> 4) * 8;
    const uint16_t* pb = Bs + buf * 4096 + (wc * 64 + (lane & 15)) * 32 + (lane >> 4) * 8;
    bf16x8 a[4], b[4];
    #pragma unroll
    for (int i = 0; i < 4; i++) a[i] = *(const bf16x8*)(pa + i * 512);
    #pragma unroll
    for (int i = 0; i < 4; i++) b[i] = *(const bf16x8*)(pb + i * 512);
    #pragma unroll
    for (int mi = 0; mi < 4; mi++)
      #pragma unroll
      for (int ni = 0; ni < 4; ni++)
        acc[mi][ni] = __builtin_amdgcn_mfma_f32_16x16x32_bf16(a[mi], b[ni], acc[mi][ni], 0, 0, 0);
  };

  // T3-minimum 2-phase: one barrier per K-step, loads in flight across compute.
  int cur = 0;
  stage(0);
  asm volatile("s_waitcnt vmcnt(0)" ::: "memory");
  __builtin_amdgcn_s_barrier();
  __builtin_amdgcn_sched_barrier(0);
  const int iters = K >> 5;
  for (int it = 0; it < iters - 1; ++it) {
    stage(cur ^ 1);
    compute(cur);
    asm volatile("s_waitcnt vmcnt(0)" ::: "memory");
    __builtin_amdgcn_s_barrier();
    __builtin_amdgcn_sched_barrier(0);
    cur ^= 1;
  }
  compute(cur);

  const int g = lane >> 4, cl = lane & 15;
  const int crow = wr * 64 + g * 4;   // + mi*16 + r
  const int ccol = wc * 64 + cl;      // + ni*16

  if (MODE == 1) {
    // direct f32 stores (64B segments), + bias
    float bvv[4];
    #pragma unroll
    for (int ni = 0; ni < 4; ni++) bvv[ni] = bias[n0 + ccol + ni * 16];
    float* C = (float*)Cout + z * cZ;
    #pragma unroll
    for (int mi = 0; mi < 4; mi++)
      #pragma unroll
      for (int r = 0; r < 4; r++) {
        size_t gr = m0 + crow + mi * 16 + r;
        #pragma unroll
        for (int ni = 0; ni < 4; ni++)
          C[gr * (size_t)ldc + n0 + ccol + ni * 16] = acc[mi][ni][r] + bvv[ni];
      }
    return;
  }

  if (MODE == 2) {
    // exp transform in-place + per-(row, 64col-chunk) partial sums
    #pragma unroll
    for (int mi = 0; mi < 4; mi++)
      #pragma unroll
      for (int r = 0; r < 4; r++) {
        float s = 0.f;
        #pragma unroll
        for (int ni = 0; ni < 4; ni++) {
          float v = __expf(acc[mi][ni][r]);
          acc[mi][ni][r] = v;
          s += v;
        }
        s += __shfl_xor(s, 1); s += __shfl_xor(s, 2);
        s += __shfl_xor(s, 4); s += __shfl_xor(s, 8);
        if (cl == 0)
          sums[z * sZ + (m0 + crow + mi * 16 + r) * 64 + bn * 2 + wc] = s;
      }
  }

  float bvv[4];
  #pragma unroll
  for (int ni = 0; ni < 4; ni++)
    bvv[ni] = (MODE == 0) ? bias[n0 + ccol + ni * 16] : 0.f;
  float scl[4][4];  // [mi][r]
  if (MODE == 3) {
    #pragma unroll
    for (int mi = 0; mi < 4; mi++)
      #pragma unroll
      for (int r = 0; r < 4; r++)
        scl[mi][r] = sums[z * sZ + m0 + crow + mi * 16 + r];
  }

  // coalesced bf16 store via LDS bounce, two 64-row halves, stride 136
  uint16_t* C = (uint16_t*)Cout + z * cZ;
  #pragma unroll
  for (int h = 0; h < 2; ++h) {
    __syncthreads();
    if (wr == h) {
      #pragma unroll
      for (int mi = 0; mi < 4; mi++)
        #pragma unroll
        for (int r = 0; r < 4; r++) {
          const int lr = mi * 16 + g * 4 + r;
          #pragma unroll
          for (int ni = 0; ni < 4; ni++) {
            float v = acc[mi][ni][r] + bvv[ni];
            if (MODE == 3) v *= scl[mi][r];
            SH[lr * 136 + ccol + ni * 16] = f2bf(v);
          }
        }
    }
    __syncthreads();
    #pragma unroll
    for (int c = 0; c < 4; ++c) {
      const int idx = t + c * 256;
      const int row = idx >> 4, c8 = idx & 15;
      *(u16x8*)(C + (m0 + h * 64 + row) * (size_t)ldc + n0 + c8 * 8) =
          *(const u16x8*)(SH + row * 136 + c8 * 8);
    }
  }
}

// inv[r] = 1 / sum_{c<64} P[r][c]
__global__ __launch_bounds__(256)
void reduce_sums(const float* __restrict__ P, float* __restrict__ inv, int rows) {
  int r = blockIdx.x * 256 + threadIdx.x;
  if (r >= rows) return;
  const float4* p4 = (const float4*)(P + (size_t)r * 64);
  float s = 0.f;
  #pragma unroll
  for (int i = 0; i < 16; ++i) { float4 v = p4[i]; s += (v.x + v.y) + (v.z + v.w); }
  inv[r] = 1.f / s;
}

// ---------------- launch ----------------

extern "C" void kernel_launch(void* const* d_in, const int* in_sizes, int n_in,
                              void* d_out, int out_size, void* d_ws, size_t ws_size,
                              hipStream_t stream) {
  const float* x   = (const float*)d_in[0];
  const float* Wq  = (const float*)d_in[1];
  const float* bq  = (const float*)d_in[2];
  const float* Wk  = (const float*)d_in[3];
  const float* bk  = (const float*)d_in[4];
  const float* Wv  = (const float*)d_in[5];
  const float* bvp = (const float*)d_in[6];
  const float* Wo  = (const float*)d_in[7];
  const float* bo  = (const float*)d_in[8];
  float* out = (float*)d_out;

  char* ws = (char*)d_ws;
  const size_t MB = (size_t)1 << 20;
  uint16_t* qkv   = (uint16_t*)(ws);               // 48 MB
  uint16_t* Vt    = (uint16_t*)(ws + 48 * MB);     // 16 MB
  uint16_t* attn  = (uint16_t*)(ws + 64 * MB);     // 16 MB
  uint16_t* wqkvT = (uint16_t*)(ws + 80 * MB);     // 1.5 MB
  uint16_t* woT   = (uint16_t*)(ws + 82 * MB);     // 0.5 MB
  float*    bqkv  = (float*)   (ws + 83 * MB);     // 6 KB
  float*    sumsP = (float*)   (ws + 84 * MB);     // 4 MB
  float*    invs  = (float*)   (ws + 88 * MB);     // 64 KB
  uint16_t* Sbuf  = (uint16_t*)(ws + 96 * MB);     // 32*nz MB
  uint16_t* xb    = (uint16_t*)(ws + 96 * MB);     // 16 MB (dead before Sbuf use)

  // batches per attention pass: 4 if scratch allows (224MB), else 2 (160MB)
  const int nz = (ws_size >= 225 * MB) ? 4 : 2;

  convert_x<<<dim3(4096), dim3(256), 0, stream>>>(x, xb);
  pack_w<<<dim3(8, 8, 3), dim3(256), 0, stream>>>(Wq, Wk, Wv, wqkvT);
  pack_wo<<<dim3(8, 8), dim3(256), 0, stream>>>(Wo, woT);
  pack_bias<<<dim3(6), dim3(256), 0, stream>>>(bq, bk, bvp, bqkv);

  // QKV: [16384,512] @ [1536,512]^T + bias -> bf16 [16384,1536]
  gemm2<0><<<dim3(1536, 1, 1), dim3(256), 0, stream>>>(
      xb, wqkvT, bqkv, qkv, nullptr,
      16384, 1536, 512, 512, 512, 1536, 0, 0, 0, 0);

  transpose_v<<<dim3(64, 8, 4), dim3(256), 0, stream>>>(qkv, Vt);

  for (int p = 0; p < 4 / nz; ++p) {
    const uint16_t* qb = qkv + (size_t)p * nz * 4096 * 1536;
    float* sp = sumsP + (size_t)p * nz * 4096 * 64;
    float* ip = invs + (size_t)p * nz * 4096;
    // P' = exp(Q K^T * scale) bf16, + partial row sums
    gemm2<2><<<dim3(1024, 1, nz), dim3(256), 0, stream>>>(
        qb, qb + 512, nullptr, Sbuf, sp,
        4096, 4096, 512, 1536, 1536, 4096,
        (long long)4096 * 1536, (long long)4096 * 1536, (long long)4096 * 4096,
        (long long)4096 * 64);
    reduce_sums<<<dim3(nz * 4096 / 256), dim3(256), 0, stream>>>(sp, ip, nz * 4096);
    // attn = (P' @ V) * inv_sum[row]
    gemm2<3><<<dim3(128, 1, nz), dim3(256), 0, stream>>>(
        Sbuf, Vt + (size_t)p * nz * 512 * 4096, nullptr,
        attn + (size_t)p * nz * 4096 * 512, ip,
        4096, 512, 4096, 4096, 4096, 512,
        (long long)4096 * 4096, (long long)512 * 4096, (long long)4096 * 512,
        4096);
  }

  // out = attn @ WoSum^T + bo  (f32)
  gemm2<1><<<dim3(512, 1, 1), dim3(256), 0, stream>>>(
      attn, woT, bo, out, nullptr,
      16384, 512, 512, 512, 512, 512, 0, 0, 0, 0);
}

// Round 3
// 272.123 us; speedup vs baseline: 1.4006x; 1.0553x over previous
//
#include <hip/hip_runtime.h>
#include <stdint.h>

#define SCALE 0.04419417382415922f  // 1/sqrt(512)

typedef __bf16 bf16x8 __attribute__((ext_vector_type(8)));
typedef float f32x4 __attribute__((ext_vector_type(4)));
typedef uint16_t u16x8 __attribute__((ext_vector_type(8)));

static __device__ __forceinline__ uint16_t f2bf(float f) {
  union { float f; uint32_t u; } v; v.f = f;
  uint32_t u = v.u;
  return (uint16_t)((u + 0x7FFFu + ((u >> 16) & 1u)) >> 16);
}

static __device__ __forceinline__ void gload16(const void* g, void* l) {
  __builtin_amdgcn_global_load_lds(
      (__attribute__((address_space(1))) void*)g,
      (__attribute__((address_space(3))) void*)l, 16, 0, 0);
}

#define P_BAR asm volatile("s_barrier" ::: "memory")
#define P_LGKM do { asm volatile("s_waitcnt lgkmcnt(0)" ::: "memory"); \
                    __builtin_amdgcn_sched_barrier(0); } while (0)

// ---------------- conversions / packing (R1/R2-verified) ----------------

__global__ __launch_bounds__(256)
void convert_x(const float* __restrict__ x, uint16_t* __restrict__ xb) {
  size_t i = ((size_t)blockIdx.x * 256 + threadIdx.x) * 8;
  float4 a = *(const float4*)(x + i);
  float4 b = *(const float4*)(x + i + 4);
  u16x8 o;
  o[0] = f2bf(a.x); o[1] = f2bf(a.y); o[2] = f2bf(a.z); o[3] = f2bf(a.w);
  o[4] = f2bf(b.x); o[5] = f2bf(b.y); o[6] = f2bf(b.z); o[7] = f2bf(b.w);
  *(u16x8*)(xb + i) = o;
}

__global__ __launch_bounds__(256)
void pack_w(const float* __restrict__ Wq, const float* __restrict__ Wk,
            const float* __restrict__ Wv, uint16_t* __restrict__ wt) {
  __shared__ float tile[64][65];
  const int k0 = blockIdx.x * 64, n0 = blockIdx.y * 64, m = blockIdx.z;
  const float* W = (m == 0) ? Wq : ((m == 1) ? Wk : Wv);
  const float scl = (m == 0) ? SCALE : 1.0f;
  const int t = threadIdx.x, r = t >> 2, c0 = (t & 3) * 16;
  #pragma unroll
  for (int j = 0; j < 4; j++) {
    float4 v = *(const float4*)&W[(size_t)(k0 + r) * 512 + n0 + c0 + j * 4];
    tile[r][c0 + j * 4 + 0] = v.x; tile[r][c0 + j * 4 + 1] = v.y;
    tile[r][c0 + j * 4 + 2] = v.z; tile[r][c0 + j * 4 + 3] = v.w;
  }
  __syncthreads();
  u16x8 o0, o1;
  #pragma unroll
  for (int e = 0; e < 8; e++) {
    o0[e] = f2bf(tile[c0 + e][r] * scl);
    o1[e] = f2bf(tile[c0 + 8 + e][r] * scl);
  }
  uint16_t* dst = wt + (size_t)(m * 512 + n0 + r) * 512 + k0 + c0;
  *(u16x8*)dst = o0;
  *(u16x8*)(dst + 8) = o1;
}

__global__ __launch_bounds__(256)
void pack_wo(const float* __restrict__ Wo, uint16_t* __restrict__ woT) {
  __shared__ float tile[64][65];
  const int k0 = blockIdx.x * 64, n0 = blockIdx.y * 64;
  const int t = threadIdx.x, r = t >> 2, c0 = (t & 3) * 16;
  float av[16];
  #pragma unroll
  for (int e = 0; e < 16; e++) av[e] = 0.f;
  for (int h = 0; h < 8; h++) {
    const float* src = &Wo[(size_t)(h * 512 + k0 + r) * 512 + n0 + c0];
    #pragma unroll
    for (int j = 0; j < 4; j++) {
      float4 v = *(const float4*)(src + j * 4);
      av[j * 4 + 0] += v.x; av[j * 4 + 1] += v.y;
      av[j * 4 + 2] += v.z; av[j * 4 + 3] += v.w;
    }
  }
  #pragma unroll
  for (int e = 0; e < 16; e++) tile[r][c0 + e] = av[e];
  __syncthreads();
  u16x8 o0, o1;
  #pragma unroll
  for (int e = 0; e < 8; e++) {
    o0[e] = f2bf(tile[c0 + e][r]);
    o1[e] = f2bf(tile[c0 + 8 + e][r]);
  }
  uint16_t* dst = woT + (size_t)(n0 + r) * 512 + k0 + c0;
  *(u16x8*)dst = o0;
  *(u16x8*)(dst + 8) = o1;
}

__global__ void pack_bias(const float* __restrict__ bq, const float* __restrict__ bk,
                          const float* __restrict__ bv, float* __restrict__ bqkv) {
  int i = blockIdx.x * 256 + threadIdx.x;
  if (i < 512) bqkv[i] = bq[i] * SCALE;
  else if (i < 1024) bqkv[i] = bk[i - 512];
  else if (i < 1536) bqkv[i] = bv[i - 1024];
}

__global__ __launch_bounds__(256)
void transpose_v(const uint16_t* __restrict__ qkv, uint16_t* __restrict__ Vt) {
  __shared__ uint16_t tile[64][72];
  const int s0 = blockIdx.x * 64, d0 = blockIdx.y * 64, b = blockIdx.z;
  const int t = threadIdx.x, r = t >> 2, c0 = (t & 3) * 16;
  const uint16_t* src = qkv + ((size_t)(b * 4096 + s0 + r)) * 1536 + 1024 + d0 + c0;
  *(u16x8*)&tile[r][c0] = *(const u16x8*)src;
  *(u16x8*)&tile[r][c0 + 8] = *(const u16x8*)(src + 8);
  __syncthreads();
  u16x8 o0, o1;
  #pragma unroll
  for (int e = 0; e < 8; e++) { o0[e] = tile[c0 + e][r]; o1[e] = tile[c0 + 8 + e][r]; }
  uint16_t* dst = Vt + ((size_t)b * 512 + d0 + r) * 4096 + s0 + c0;
  *(u16x8*)dst = o0;
  *(u16x8*)(dst + 8) = o1;
}

// =================== 256x{256|128} 8-phase GEMM: C = A @ Bt^T ===================
// 8 waves (2M x 4N), BK=64, double-buffered LDS, counted vmcnt, XOR swizzle.
// MODE 0: bf16 out +bias | 1: f32 out +bias | 2: exp()->bf16 + row-sum partials
// MODE 3: bf16 out scaled by inv[row]
template<int BN, int MODE>
__global__ __launch_bounds__(512, 2)
void gemm8(const uint16_t* __restrict__ A, const uint16_t* __restrict__ Bt,
           const float* __restrict__ bias, void* __restrict__ Cout,
           float* __restrict__ sums,
           int M, int N, int K, int lda, int ldb, int ldc,
           long long aZ, long long bZ, long long cZ, long long sZ) {
  constexpr int NREP = BN / 64;   // acc frags per wave in N (4 or 2)
  constexpr int NH = NREP / 2;    // frags per quadrant (2 or 1)
  constexpr int WN = BN / 4;      // wave N extent (64 or 32)
  constexpr int BELTS = BN * 64;  // B slot elements
  __shared__ uint16_t SH[32768 + 2 * BELTS];  // A: 2x16384 | B: 2xBELTS

  const int nbn = N / BN;
  const int nwg = (M >> 8) * nbn;
  int id = blockIdx.x;
  id = (id & 7) * (nwg >> 3) + (id >> 3);  // XCD swizzle (all nwg % 8 == 0)
  const int bm = id / nbn, bn = id % nbn;
  const long long z = blockIdx.z;
  A += z * aZ; Bt += z * bZ;
  const size_t m0 = (size_t)bm * 256, n0 = (size_t)bn * BN;

  const int t = threadIdx.x;
  const int lane = t & 63, w = t >> 6;
  const int wr = w >> 2, wc = w & 3;
  const int l15 = lane & 15, l4 = lane >> 4, l7 = lane & 7, l3 = lane >> 3;
  const int sw = l7 ^ l3;  // pre-swizzled source colgrp (inverse of read XOR)

  // staging source base pointers (per-lane)
  const uint16_t* srcA = A + (m0 + w * 8 + l3) * (size_t)lda + sw * 8;
  const uint16_t* srcB = (BN == 256)
      ? Bt + (n0 + (w >> 1) * 64 + (w & 1) * 16 + l3) * (size_t)ldb + sw * 8
      : Bt + (n0 + (w >> 1) * 32 + (w & 1) * 8 + l3) * (size_t)ldb + sw * 8;

  const int NKT = K >> 6;   // 64-wide K tiles (callers guarantee NKT even, >= 4)
  const int NIT = NKT >> 1;

  f32x4 acc[8][NREP];
  #pragma unroll
  for (int i = 0; i < 8; i++)
    #pragma unroll
    for (int j = 0; j < NREP; j++) acc[i][j] = (f32x4)(0.f);

  bf16x8 a[4][2], b0[NH][2], b1[NH][2];

  // stage quadrant-region half-tiles; LDS linear, source pre-swizzled
  auto stageA = [&](int tile, int mh) {
    const uint16_t* s = srcA + mh * 64 * (size_t)lda + tile * 64;
    uint16_t* d = SH + (tile & 1) * 16384 + mh * 4096 + w * 512;
    gload16(s, d);
    gload16(s + 128 * (size_t)lda, d + 8192);
  };
  auto stageB = [&](int tile, int nh) {
    if (BN == 256) {
      const uint16_t* s = srcB + nh * 32 * (size_t)ldb + tile * 64;
      uint16_t* d = SH + 32768 + (tile & 1) * BELTS + (w >> 1) * 4096 + nh * 2048 + (w & 1) * 1024;
      gload16(s, d);
      gload16(s + 8 * (size_t)ldb, d + 512);
    } else {
      const uint16_t* s = srcB + nh * 16 * (size_t)ldb + tile * 64;
      uint16_t* d = SH + 32768 + (tile & 1) * BELTS + (w >> 1) * 2048 + nh * 1024 + (w & 1) * 512;
      gload16(s, d);
    }
  };
  auto loadA = [&](int buf, int mh) {
    const uint16_t* base = SH + buf * 16384 + (wr * 128 + mh * 64 + l15) * 64;
    #pragma unroll
    for (int m = 0; m < 4; m++)
      #pragma unroll
      for (int ks = 0; ks < 2; ks++)
        a[m][ks] = *(const bf16x8*)(base + m * 1024 + (((ks * 4 + l4) ^ l7) * 8));
  };
  auto loadB = [&](int buf, int nh, bf16x8 (&bd)[NH][2]) {
    const uint16_t* base = SH + 32768 + buf * BELTS + (wc * WN + nh * (WN / 2) + l15) * 64;
    #pragma unroll
    for (int n = 0; n < NH; n++)
      #pragma unroll
      for (int ks = 0; ks < 2; ks++)
        bd[n][ks] = *(const bf16x8*)(base + n * 1024 + (((ks * 4 + l4) ^ l7) * 8));
  };
  auto quad = [&](int mh, int nq, bf16x8 (&bq)[NH][2]) {
    __builtin_amdgcn_s_setprio(1);
    #pragma unroll
    for (int m = 0; m < 4; m++)
      #pragma unroll
      for (int n = 0; n < NH; n++)
        #pragma unroll
        for (int ks = 0; ks < 2; ks++)
          acc[mh * 4 + m][nq + n] = __builtin_amdgcn_mfma_f32_16x16x32_bf16(
              a[m][ks], bq[n][ks], acc[mh * 4 + m][nq + n], 0, 0, 0);
    __builtin_amdgcn_s_setprio(0);
  };

  // ---- prologue: tile0 full + tile1 {A0,B0,A1}; wait tile0 landed ----
  stageA(0, 0); stageB(0, 0); stageA(0, 1); stageB(0, 1);
  stageA(1, 0); stageB(1, 0); stageA(1, 1);
  if (BN == 256) asm volatile("s_waitcnt vmcnt(6)" ::: "memory");
  else           asm volatile("s_waitcnt vmcnt(5)" ::: "memory");
  P_BAR;

  // ---- main loop: 8 phases per 2 K-tiles ----
  for (int k = 0; k < NIT - 1; ++k) {
    const int tt = 2 * k;
    // P1
    loadA(0, 0); loadB(0, 0, b0); stageB(tt + 1, 1);
    P_BAR; P_LGKM; quad(0, 0, b0); P_BAR;
    // P2
    loadB(0, 1, b1); stageA(tt + 2, 0);
    P_BAR; P_LGKM; quad(0, NH, b1); P_BAR;
    // P3
    loadA(0, 1); stageB(tt + 2, 0);
    P_BAR; P_LGKM; quad(1, NH, b1); P_BAR;
    // P4
    stageA(tt + 2, 1);
    if (BN == 256) asm volatile("s_waitcnt vmcnt(6)" ::: "memory");
    else           asm volatile("s_waitcnt vmcnt(5)" ::: "memory");
    P_BAR; quad(1, 0, b0); P_BAR;
    // P5
    loadA(1, 0); loadB(1, 0, b0); stageB(tt + 2, 1);
    P_BAR; P_LGKM; quad(0, 0, b0); P_BAR;
    // P6
    loadB(1, 1, b1); stageA(tt + 3, 0);
    P_BAR; P_LGKM; quad(0, NH, b1); P_BAR;
    // P7
    loadA(1, 1); stageB(tt + 3, 0);
    P_BAR; P_LGKM; quad(1, NH, b1); P_BAR;
    // P8
    stageA(tt + 3, 1);
    if (BN == 256) asm volatile("s_waitcnt vmcnt(6)" ::: "memory");
    else           asm volatile("s_waitcnt vmcnt(5)" ::: "memory");
    P_BAR; quad(1, 0, b0); P_BAR;
  }
  // ---- last iteration (tiles NKT-2, NKT-1), staging done except B1@NKT-1 ----
  loadA(0, 0); loadB(0, 0, b0); stageB(NKT - 1, 1);
  P_BAR; P_LGKM; quad(0, 0, b0); P_BAR;
  loadB(0, 1, b1);
  P_BAR; P_LGKM; quad(0, NH, b1); P_BAR;
  loadA(0, 1);
  P_BAR; P_LGKM; quad(1, NH, b1); P_BAR;
  asm volatile("s_waitcnt vmcnt(0)" ::: "memory");
  P_BAR; quad(1, 0, b0); P_BAR;
  loadA(1, 0); loadB(1, 0, b0);
  P_BAR; P_LGKM; quad(0, 0, b0); P_BAR;
  loadB(1, 1, b1);
  P_BAR; P_LGKM; quad(0, NH, b1); P_BAR;
  loadA(1, 1);
  P_BAR; P_LGKM; quad(1, NH, b1); P_BAR;
  quad(1, 0, b0);

  // ---- epilogue ----
  asm volatile("s_waitcnt vmcnt(0) lgkmcnt(0)" ::: "memory");
  __syncthreads();

  const int g = l4;  // C/D: col = lane&15, row = (lane>>4)*4 + reg

  if (MODE == 1) {
    float bvv[NREP];
    #pragma unroll
    for (int ni = 0; ni < NREP; ni++) bvv[ni] = bias[n0 + wc * WN + ni * 16 + l15];
    float* C = (float*)Cout + z * cZ;
    #pragma unroll
    for (int am = 0; am < 8; am++)
      #pragma unroll
      for (int r = 0; r < 4; r++) {
        size_t gr = m0 + wr * 128 + am * 16 + g * 4 + r;
        #pragma unroll
        for (int ni = 0; ni < NREP; ni++)
          C[gr * (size_t)ldc + n0 + wc * WN + ni * 16 + l15] = acc[am][ni][r] + bvv[ni];
      }
    return;
  }

  if (MODE == 2) {  // exp + per-(row, 64col) partial sums (BN==256 only)
    #pragma unroll
    for (int am = 0; am < 8; am++)
      #pragma unroll
      for (int r = 0; r < 4; r++) {
        float s = 0.f;
        #pragma unroll
        for (int ni = 0; ni < NREP; ni++) {
          float v = __expf(acc[am][ni][r]);
          acc[am][ni][r] = v;
          s += v;
        }
        s += __shfl_xor(s, 1); s += __shfl_xor(s, 2);
        s += __shfl_xor(s, 4); s += __shfl_xor(s, 8);
        if (l15 == 0)
          sums[z * sZ + (m0 + wr * 128 + am * 16 + g * 4 + r) * 64 + (n0 >> 6) + wc] = s;
      }
  }

  float bvv[NREP];
  #pragma unroll
  for (int ni = 0; ni < NREP; ni++)
    bvv[ni] = (MODE == 0) ? bias[n0 + wc * WN + ni * 16 + l15] : 0.f;
  float4 sc[8];
  if (MODE == 3) {
    #pragma unroll
    for (int am = 0; am < 8; am++)
      sc[am] = *(const float4*)&sums[z * sZ + m0 + wr * 128 + am * 16 + g * 4];
  }

  // coalesced bf16 store via LDS bounce, two 128-row halves
  constexpr int STR = BN + 8;
  uint16_t* C16 = (uint16_t*)Cout + z * cZ;
  #pragma unroll
  for (int h = 0; h < 2; ++h) {
    __syncthreads();
    if (wr == h) {
      #pragma unroll
      for (int am = 0; am < 8; am++)
        #pragma unroll
        for (int r = 0; r < 4; r++) {
          const int lr = am * 16 + g * 4 + r;
          #pragma unroll
          for (int ni = 0; ni < NREP; ni++) {
            float v = acc[am][ni][r] + bvv[ni];
            if (MODE == 3) v *= ((const float*)&sc[am])[r];
            SH[lr * STR + wc * WN + ni * 16 + l15] = f2bf(v);
          }
        }
    }
    __syncthreads();
    constexpr int CPT = BN / 32;  // b128 chunks per thread (8 or 4)
    #pragma unroll
    for (int c = 0; c < CPT; ++c) {
      const int idx = t + c * 512;
      const int row = idx / (BN / 8), c8 = idx % (BN / 8);
      *(u16x8*)(C16 + (m0 + h * 128 + row) * (size_t)ldc + n0 + c8 * 8) =
          *(const u16x8*)(SH + row * STR + c8 * 8);
    }
  }
}

// inv[r] = 1 / sum_{c<64} P[r][c]
__global__ __launch_bounds__(256)
void reduce_sums(const float* __restrict__ P, float* __restrict__ inv, int rows) {
  int r = blockIdx.x * 256 + threadIdx.x;
  if (r >= rows) return;
  const float4* p4 = (const float4*)(P + (size_t)r * 64);
  float s = 0.f;
  #pragma unroll
  for (int i = 0; i < 16; ++i) { float4 v = p4[i]; s += (v.x + v.y) + (v.z + v.w); }
  inv[r] = 1.f / s;
}

// ---------------- launch ----------------

extern "C" void kernel_launch(void* const* d_in, const int* in_sizes, int n_in,
                              void* d_out, int out_size, void* d_ws, size_t ws_size,
                              hipStream_t stream) {
  const float* x   = (const float*)d_in[0];
  const float* Wq  = (const float*)d_in[1];
  const float* bq  = (const float*)d_in[2];
  const float* Wk  = (const float*)d_in[3];
  const float* bk  = (const float*)d_in[4];
  const float* Wv  = (const float*)d_in[5];
  const float* bvp = (const float*)d_in[6];
  const float* Wo  = (const float*)d_in[7];
  const float* bo  = (const float*)d_in[8];
  float* out = (float*)d_out;

  char* ws = (char*)d_ws;
  const size_t MB = (size_t)1 << 20;
  uint16_t* qkv   = (uint16_t*)(ws);               // 48 MB
  uint16_t* Vt    = (uint16_t*)(ws + 48 * MB);     // 16 MB
  uint16_t* attn  = (uint16_t*)(ws + 64 * MB);     // 16 MB
  uint16_t* wqkvT = (uint16_t*)(ws + 80 * MB);     // 1.5 MB
  uint16_t* woT   = (uint16_t*)(ws + 82 * MB);     // 0.5 MB
  float*    bqkv  = (float*)   (ws + 83 * MB);     // 6 KB
  float*    sumsP = (float*)   (ws + 84 * MB);     // 4 MB
  float*    invs  = (float*)   (ws + 88 * MB);     // 64 KB
  uint16_t* Sbuf  = (uint16_t*)(ws + 96 * MB);     // 32*nz MB
  uint16_t* xb    = (uint16_t*)(ws + 96 * MB);     // 16 MB (dead before Sbuf use)

  const int nz = (ws_size >= 225 * MB) ? 4 : 2;

  convert_x<<<dim3(4096), dim3(256), 0, stream>>>(x, xb);
  pack_w<<<dim3(8, 8, 3), dim3(256), 0, stream>>>(Wq, Wk, Wv, wqkvT);
  pack_wo<<<dim3(8, 8), dim3(256), 0, stream>>>(Wo, woT);
  pack_bias<<<dim3(6), dim3(256), 0, stream>>>(bq, bk, bvp, bqkv);

  // QKV: [16384,512] @ [1536,512]^T + bias -> bf16 [16384,1536]
  gemm8<256, 0><<<dim3(384, 1, 1), dim3(512), 0, stream>>>(
      xb, wqkvT, bqkv, qkv, nullptr,
      16384, 1536, 512, 512, 512, 1536, 0, 0, 0, 0);

  transpose_v<<<dim3(64, 8, 4), dim3(256), 0, stream>>>(qkv, Vt);

  for (int p = 0; p < 4 / nz; ++p) {
    const uint16_t* qb = qkv + (size_t)p * nz * 4096 * 1536;
    float* sp = sumsP + (size_t)p * nz * 4096 * 64;
    float* ip = invs + (size_t)p * nz * 4096;
    // P' = exp(Q K^T * scale) bf16 + partial row sums
    gemm8<256, 2><<<dim3(256, 1, nz), dim3(512), 0, stream>>>(
        qb, qb + 512, nullptr, Sbuf, sp,
        4096, 4096, 512, 1536, 1536, 4096,
        (long long)4096 * 1536, (long long)4096 * 1536, (long long)4096 * 4096,
        (long long)4096 * 64);
    reduce_sums<<<dim3(nz * 4096 / 256), dim3(256), 0, stream>>>(sp, ip, nz * 4096);
    // attn = (P' @ V) * inv_sum[row]
    gemm8<128, 3><<<dim3(64, 1, nz), dim3(512), 0, stream>>>(
        Sbuf, Vt + (size_t)p * nz * 512 * 4096, nullptr,
        attn + (size_t)p * nz * 4096 * 512, ip,
        4096, 512, 4096, 4096, 4096, 512,
        (long long)4096 * 4096, (long long)512 * 4096, (long long)4096 * 512,
        4096);
  }

  // out = attn @ WoSum^T + bo  (f32)
  gemm8<128, 1><<<dim3(256, 1, 1), dim3(512), 0, stream>>>(
      attn, woT, bo, out, nullptr,
      16384, 512, 512, 512, 512, 512, 0, 0, 0, 0);
}